// Round 6
// baseline (44.159 us; speedup 1.0000x reference)
//
#include <hip/hip_runtime.h>
#include <hip/hip_bf16.h>

// SimCLR loss, MI355X. N=8192 rows, D=128, T=0.5.
// normalize(f32->bf16) -> SYMMETRIC fused sim-GEMM + sum(exp(2*dot)):
// only upper-triangle 256x256 block-pairs (I<=J) are computed; each off-diag
// block contributes its exp-tile row-wise to rows(I) and column-wise to
// rows(J) (sim is symmetric). Halves MFMA/LDS/exp work vs full square.
// Fixed-max logsumexp (|sim|<=2 after normalization) -> no online max.
// -> per-row loss + pos-dot -> scalar reduce.

#define BATCH 4096
#define N_TOT 8192
#define DIM 128
#define ROWS_PER_WAVE 32
#define WAVES_PER_BLK 8
#define ROWS_PER_BLK 256                  // 8 waves x 32 rows
#define NGRP 32                           // 8192 / 256 row-groups
#define NPAIR ((NGRP * (NGRP + 1)) / 2)   // 528 upper-triangle pair blocks
#define TILE_C 64                         // cols per LDS B-tile (16 KB)
#define NT 4                              // 256-col group = 4 tiles

// exp(2d) == exp2(d * 2/ln2)
#define C_LOG2E2 2.8853900817779268f

using bf16x8 = __attribute__((ext_vector_type(8))) __bf16;
using f32x4  = __attribute__((ext_vector_type(4))) float;

typedef __attribute__((address_space(1))) const void cg_void;
typedef __attribute__((address_space(3))) void lds_void;
__device__ __forceinline__ void gll16(const void* g, void* l) {
    __builtin_amdgcn_global_load_lds((cg_void*)g, (lds_void*)l, 16, 0, 0);
}

// ---------------- kernel 1: normalize rows, write bf16 ----------------
__global__ __launch_bounds__(256) void k_normalize(const float* __restrict__ zi,
                                                   const float* __restrict__ zj,
                                                   __hip_bfloat16* __restrict__ zn) {
    int row  = blockIdx.x * 4 + (threadIdx.x >> 6);
    int lane = threadIdx.x & 63;
    const float* src = (row < BATCH) ? (zi + (size_t)row * DIM)
                                     : (zj + (size_t)(row - BATCH) * DIM);
    float2 v = ((const float2*)src)[lane];
    float ss = v.x * v.x + v.y * v.y;
    #pragma unroll
    for (int m = 1; m < 64; m <<= 1) ss += __shfl_xor(ss, m);
    float inv = 1.0f / fmaxf(sqrtf(ss), 1e-8f);
    __hip_bfloat162 o;
    o.x = __float2bfloat16(v.x * inv);
    o.y = __float2bfloat16(v.y * inv);
    ((__hip_bfloat162*)(zn + (size_t)row * DIM))[lane] = o;
}

// ---------------- kernel 2: symmetric sim GEMM + exp row/col sums ----------------
// Block (I,J), I<=J: A = rows of I (regs, 32/wave), B = 256 cols of J staged in
// LDS (64-col tiles, double-buffered, XOR-swizzled: linear LDS dest +
// inverse-swizzled global src + swizzled ds_read).
// S_contrib[slot][row]: rowsum part -> slot J rows of I; colsum part -> slot I
// rows of J. Each (slot,row) written by exactly one block -> deterministic.
__global__ __launch_bounds__(512, 4) void k_main(const __hip_bfloat16* __restrict__ zn_,
                                                 float* __restrict__ S_contrib) {
    __shared__ __align__(16) char Bs[2][TILE_C * 256];   // 32 KB
    __shared__ float colred[WAVES_PER_BLK][ROWS_PER_BLK]; // 8 KB wave-partial colsums

    const int tid  = threadIdx.x;
    const int lane = tid & 63;
    const int wv   = tid >> 6;                        // 0..7
    const int l15  = lane & 15;
    const int lb   = lane >> 4;                       // 0..3

    // decode upper-triangle pair (I,J) from blockIdx.x
    int I = 0, rem = blockIdx.x;
    while (rem >= NGRP - I) { rem -= NGRP - I; ++I; }
    const int J = I + rem;
    const bool isdiag = (I == J);

    const int wr0 = I * ROWS_PER_BLK + wv * ROWS_PER_WAVE;
    const int cs0 = J * ROWS_PER_BLK;

    const __bf16* zn = (const __bf16*)zn_;

    // A fragments: rows wr0 + g*16 + l15 (g=0,1), k-slice s: k = s*32 + lb*8..+7
    bf16x8 a_[2][4];
    #pragma unroll
    for (int g = 0; g < 2; ++g) {
        const __bf16* p = zn + (size_t)(wr0 + g * 16 + l15) * DIM + lb * 8;
        #pragma unroll
        for (int s = 0; s < 4; ++s)
            a_[g][s] = *(const bf16x8*)(p + s * 32);
    }

    ((float4*)colred)[tid] = float4{0.f, 0.f, 0.f, 0.f};  // zero 8 KB (512*16B)

    // staging: 1024 granules of 16B per tile; 512 threads -> 2 each.
    // LDS granule (c, slot) at c*256+slot*16 holds global k-chunk j = slot^(c&7)
    const char* gB = (const char*)(zn + (size_t)cs0 * DIM);
    int srcoff[2];
    #pragma unroll
    for (int i = 0; i < 2; ++i) {
        int m = i * 512 + tid;
        int c = m >> 4, slot = m & 15;
        int j = slot ^ (c & 7);
        srcoff[i] = c * 256 + j * 16;
    }

    auto STAGE = [&](int t) {
        const char* src = gB + (size_t)t * (TILE_C * 256);
        char* dst = Bs[t & 1];
        #pragma unroll
        for (int i = 0; i < 2; ++i)   // LDS dest: wave-uniform base + lane*16
            gll16(src + srcoff[i], dst + i * 8192 + wv * 1024);
    };

    f32x4 sumexp[2] = {};                             // row-direction sums

    auto COMPUTE = [&](int t) {
        const char* buf = Bs[t & 1];
        const int c0t = cs0 + t * TILE_C;
        const bool diagtile = ((unsigned)(wr0 - c0t) < (unsigned)TILE_C); // wave-uniform
        #pragma unroll
        for (int cb = 0; cb < 4; ++cb) {
            const int c = cb * 16 + l15;              // local col
            const char* pc = buf + c * 256;
            bf16x8 b[4];
            #pragma unroll
            for (int s = 0; s < 4; ++s)
                b[s] = *(const bf16x8*)(pc + ((lb + s * 4) ^ (c & 7)) * 16);
            f32x4 acc[2] = {};
            #pragma unroll
            for (int g = 0; g < 2; ++g)
                #pragma unroll
                for (int s = 0; s < 4; ++s)
                    acc[g] = __builtin_amdgcn_mfma_f32_16x16x32_bf16(a_[g][s], b[s], acc[g], 0, 0, 0);
            // C layout: col = c0t+c, row = wr0+g*16+lb*4+v
            const int mycol = c0t + c;
            if (diagtile) {                           // only occurs when isdiag
                #pragma unroll
                for (int g = 0; g < 2; ++g)
                    #pragma unroll
                    for (int v = 0; v < 4; ++v) {
                        float e = __builtin_amdgcn_exp2f(acc[g][v] * C_LOG2E2);
                        int row = wr0 + g * 16 + lb * 4 + v;
                        sumexp[g][v] += (mycol == row) ? 0.0f : e;   // exclude self
                    }
            } else {
                float cs = 0.0f;                      // col-direction partial (32 rows)
                #pragma unroll
                for (int g = 0; g < 2; ++g)
                    #pragma unroll
                    for (int v = 0; v < 4; ++v) {
                        float e = __builtin_amdgcn_exp2f(acc[g][v] * C_LOG2E2);
                        sumexp[g][v] += e;
                        cs += e;
                    }
                if (!isdiag) {
                    cs += __shfl_xor(cs, 16);         // reduce over lb groups
                    cs += __shfl_xor(cs, 32);
                    if (lb == 0)                      // 16 lanes deposit 16 cols
                        colred[wv][t * TILE_C + cb * 16 + l15] += cs;
                }
            }
        }
    };

    STAGE(0);
    __syncthreads();                                  // colred init + tile 0 ready
    #pragma unroll
    for (int t = 0; t < NT; ++t) {
        if (t + 1 < NT) STAGE(t + 1);                 // prefetch; drained at barrier
        COMPUTE(t);
        if (t + 1 < NT) __syncthreads();              // guards buffer swap
    }

    // row-direction: reduce across the 16 lanes (cols) sharing each row
    #pragma unroll
    for (int m = 1; m <= 8; m <<= 1)
        #pragma unroll
        for (int g = 0; g < 2; ++g)
            #pragma unroll
            for (int v = 0; v < 4; ++v)
                sumexp[g][v] += __shfl_xor(sumexp[g][v], m);

    if (l15 == 0) {
        #pragma unroll
        for (int g = 0; g < 2; ++g) {
            int row = wr0 + g * 16 + lb * 4;
            *(f32x4*)&S_contrib[(size_t)J * N_TOT + row] = sumexp[g];
        }
    }

    // col-direction: combine the 8 waves' partials, write to slot I rows of J
    if (!isdiag) {
        __syncthreads();
        if (tid < ROWS_PER_BLK) {
            float s = 0.0f;
            #pragma unroll
            for (int w = 0; w < WAVES_PER_BLK; ++w) s += colred[w][tid];
            S_contrib[(size_t)I * N_TOT + cs0 + tid] = s;
        }
    }
}

// bf16-pair dot helper (uint = 2 packed bf16)
__device__ inline float bdot(unsigned a, unsigned b) {
    float alo = __uint_as_float(a << 16), ahi = __uint_as_float(a & 0xffff0000u);
    float blo = __uint_as_float(b << 16), bhi = __uint_as_float(b & 0xffff0000u);
    return fmaf(alo, blo, ahi * bhi);
}

// ---------------- kernel 3: per-row loss, block partials ----------------
// contrib_r = log(S_r) - 2*dot(zn_r, zn_partner), S_r = sum_{c!=r} exp(2*cos)
__global__ __launch_bounds__(256) void k_rowsum(const float* __restrict__ S_contrib,
                                                const __hip_bfloat16* __restrict__ zn_,
                                                float* __restrict__ blk_out) {
    const int r = blockIdx.x * 256 + threadIdx.x;
    float S = 0.0f;
    #pragma unroll
    for (int s = 0; s < NGRP; ++s) S += S_contrib[(size_t)s * N_TOT + r];

    const uint4* pa = (const uint4*)((const __bf16*)zn_ + (size_t)r * DIM);
    const uint4* pb = (const uint4*)((const __bf16*)zn_ + (size_t)(r ^ BATCH) * DIM);
    float dot = 0.0f;
    #pragma unroll
    for (int c = 0; c < DIM / 8; ++c) {
        uint4 ua = pa[c], ub = pb[c];
        dot += bdot(ua.x, ub.x) + bdot(ua.y, ub.y) + bdot(ua.z, ub.z) + bdot(ua.w, ub.w);
    }

    float contrib = __logf(S) - 2.0f * dot;

    #pragma unroll
    for (int m = 1; m < 64; m <<= 1) contrib += __shfl_xor(contrib, m);
    __shared__ float sm[4];
    if ((threadIdx.x & 63) == 0) sm[threadIdx.x >> 6] = contrib;
    __syncthreads();
    if (threadIdx.x == 0) blk_out[blockIdx.x] = sm[0] + sm[1] + sm[2] + sm[3];
}

// ---------------- kernel 4: final scalar ----------------
__global__ void k_final(const float* __restrict__ blk_out, float* __restrict__ out) {
    float v = (threadIdx.x < NGRP) ? blk_out[threadIdx.x] : 0.0f;
    #pragma unroll
    for (int m = 1; m < 64; m <<= 1) v += __shfl_xor(v, m);
    if (threadIdx.x == 0) out[0] = v / (float)N_TOT;
}

extern "C" void kernel_launch(void* const* d_in, const int* in_sizes, int n_in,
                              void* d_out, int out_size, void* d_ws, size_t ws_size,
                              hipStream_t stream) {
    const float* zi = (const float*)d_in[0];
    const float* zj = (const float*)d_in[1];
    char* ws = (char*)d_ws;
    __hip_bfloat16* zn = (__hip_bfloat16*)ws;                        // 2 MB
    float* S_contrib = (float*)(ws + (size_t)2 * 1024 * 1024);       // 1 MB
    float* blk       = (float*)(ws + (size_t)3 * 1024 * 1024);       // 128 B
    float* out       = (float*)d_out;

    k_normalize<<<N_TOT / 4, 256, 0, stream>>>(zi, zj, zn);
    k_main<<<NPAIR, 512, 0, stream>>>(zn, S_contrib);
    k_rowsum<<<NGRP, 256, 0, stream>>>(S_contrib, zn, blk);
    k_final<<<1, 64, 0, stream>>>(blk, out);
}

// Round 7
// 37.547 us; speedup vs baseline: 1.1761x; 1.1761x over previous
//
#include <hip/hip_runtime.h>
#include <hip/hip_bf16.h>
#include <type_traits>

// SimCLR loss, MI355X. N=8192 rows, D=128, T=0.5.
// normalize(f32->bf16) -> SYMMETRIC sim-GEMM + sum(exp(2*dot)) over the
// 128-row-group upper triangle (2080 pair-blocks; fine granularity so dynamic
// dispatch balances: R6's 528x256-row blocks lost the symmetry win to a
// 1.45x scheduling tail) -> per-row loss + pos-dot -> scalar reduce.
// Fixed-max logsumexp (|sim|<=2) -> no online max needed.

#define BATCH 4096
#define N_TOT 8192
#define DIM 128
#define ROWS_PER_WAVE 32
#define WAVES_PER_BLK 4
#define GRP 128                           // rows per group
#define NGRP 64                           // 8192 / 128
#define NPAIR ((NGRP * (NGRP + 1)) / 2)   // 2080 upper-triangle pair blocks
#define TILE_C 64                         // cols per LDS B-tile (16 KB)
#define NROWBLK 32                        // k_rowsum blocks (8192/256)

// exp(2d) == exp2(d * 2/ln2)
#define C_LOG2E2 2.8853900817779268f

using bf16x8 = __attribute__((ext_vector_type(8))) __bf16;
using f32x4  = __attribute__((ext_vector_type(4))) float;

typedef __attribute__((address_space(1))) const void cg_void;
typedef __attribute__((address_space(3))) void lds_void;
__device__ __forceinline__ void gll16(const void* g, void* l) {
    __builtin_amdgcn_global_load_lds((cg_void*)g, (lds_void*)l, 16, 0, 0);
}

// ---------------- kernel 1: normalize rows, write bf16 ----------------
__global__ __launch_bounds__(256) void k_normalize(const float* __restrict__ zi,
                                                   const float* __restrict__ zj,
                                                   __hip_bfloat16* __restrict__ zn) {
    int row  = blockIdx.x * 4 + (threadIdx.x >> 6);
    int lane = threadIdx.x & 63;
    const float* src = (row < BATCH) ? (zi + (size_t)row * DIM)
                                     : (zj + (size_t)(row - BATCH) * DIM);
    float2 v = ((const float2*)src)[lane];
    float ss = v.x * v.x + v.y * v.y;
    #pragma unroll
    for (int m = 1; m < 64; m <<= 1) ss += __shfl_xor(ss, m);
    float inv = 1.0f / fmaxf(sqrtf(ss), 1e-8f);
    __hip_bfloat162 o;
    o.x = __float2bfloat16(v.x * inv);
    o.y = __float2bfloat16(v.y * inv);
    ((__hip_bfloat162*)(zn + (size_t)row * DIM))[lane] = o;
}

// ---------------- kernel 2: symmetric sim GEMM + exp row/col sums ----------------
// Block (I,J), I<=J: A = 128 rows of I (regs, 32/wave over 4 waves), B = 128
// cols of J in LDS (2 x 64-col tiles, XOR-swizzled; linear LDS dest +
// inverse-swizzled global src + swizzled ds_read). Both tiles staged up
// front -> ONE barrier -> straight compute. Off-diag blocks also bank the
// column-direction exp sums (8 static registers/lane, LDS combine at end).
// S_contrib[slot][row]: row r of group I gets slot J (rowsum) / slot J' < I
// (colsum of block (J',I)); each (slot,row) has exactly one writer.
__global__ __launch_bounds__(256, 4) void k_main(const __hip_bfloat16* __restrict__ zn_,
                                                 float* __restrict__ S_contrib) {
    __shared__ __align__(16) char Bs[2][TILE_C * 256];       // 32 KB
    __shared__ float colred[WAVES_PER_BLK][GRP];             // 2 KB

    const int tid  = threadIdx.x;
    const int lane = tid & 63;
    const int wv   = tid >> 6;                        // 0..3
    const int l15  = lane & 15;
    const int lb   = lane >> 4;                       // 0..3

    // decode upper-triangle pair (I,J) from blockIdx.x
    int I = 0, rem = blockIdx.x;
    while (rem >= NGRP - I) { rem -= NGRP - I; ++I; }
    const int J = I + rem;
    const bool isdiag = (I == J);

    const int wr0 = I * GRP + wv * ROWS_PER_WAVE;
    const int cs0 = J * GRP;

    const __bf16* zn = (const __bf16*)zn_;

    // A fragments: rows wr0 + g*16 + l15 (g=0,1), k-slice s: k = s*32 + lb*8..+7
    bf16x8 a_[2][4];
    #pragma unroll
    for (int g = 0; g < 2; ++g) {
        const __bf16* p = zn + (size_t)(wr0 + g * 16 + l15) * DIM + lb * 8;
        #pragma unroll
        for (int s = 0; s < 4; ++s)
            a_[g][s] = *(const bf16x8*)(p + s * 32);
    }

    // staging: 1024 granules of 16B per tile; 256 threads -> 4 each.
    // LDS granule (c, slot) at c*256+slot*16 holds global k-chunk j = slot^(c&7)
    const char* gB = (const char*)(zn + (size_t)cs0 * DIM);
    int srcoff[4];
    #pragma unroll
    for (int i = 0; i < 4; ++i) {
        int m = (wv * 4 + i) * 64 + lane;
        int c = m >> 4, slot = m & 15;
        int j = slot ^ (c & 7);
        srcoff[i] = c * 256 + j * 16;
    }

    #pragma unroll
    for (int t = 0; t < 2; ++t) {                     // stage BOTH tiles up front
        const char* src = gB + (size_t)t * (TILE_C * 256);
        #pragma unroll
        for (int i = 0; i < 4; ++i)                   // LDS dest: uniform + lane*16
            gll16(src + srcoff[i], Bs[t] + (wv * 4 + i) * 1024);
    }

    f32x4 sumexp[2] = {};                             // row-direction sums
    float csr[8] = {};                                // col-direction partials

    __syncthreads();                                  // drains all gll16 (vmcnt 0)

    auto COMPUTE = [&](auto tc) {
        constexpr int t = tc.value;
        const char* buf = Bs[t];
        const int c0t = cs0 + t * TILE_C;
        const bool diagtile = ((unsigned)(wr0 - c0t) < (unsigned)TILE_C); // wave-uniform
        #pragma unroll
        for (int cb = 0; cb < 4; ++cb) {
            const int c = cb * 16 + l15;              // local col
            const char* pc = buf + c * 256;
            bf16x8 b[4];
            #pragma unroll
            for (int s = 0; s < 4; ++s)
                b[s] = *(const bf16x8*)(pc + ((lb + s * 4) ^ (c & 7)) * 16);
            f32x4 acc[2] = {};
            #pragma unroll
            for (int g = 0; g < 2; ++g)
                #pragma unroll
                for (int s = 0; s < 4; ++s)
                    acc[g] = __builtin_amdgcn_mfma_f32_16x16x32_bf16(a_[g][s], b[s], acc[g], 0, 0, 0);
            // C layout: col = c0t+c, row = wr0+g*16+lb*4+v
            const int mycol = c0t + c;
            if (diagtile) {                           // only inside diag blocks
                #pragma unroll
                for (int g = 0; g < 2; ++g)
                    #pragma unroll
                    for (int v = 0; v < 4; ++v) {
                        float e = __builtin_amdgcn_exp2f(acc[g][v] * C_LOG2E2);
                        int row = wr0 + g * 16 + lb * 4 + v;
                        sumexp[g][v] += (mycol == row) ? 0.0f : e;   // exclude self
                    }
            } else {
                float cs = 0.0f;
                #pragma unroll
                for (int g = 0; g < 2; ++g)
                    #pragma unroll
                    for (int v = 0; v < 4; ++v) {
                        float e = __builtin_amdgcn_exp2f(acc[g][v] * C_LOG2E2);
                        sumexp[g][v] += e;
                        cs += e;
                    }
                csr[t * 4 + cb] += cs;                // static index (t,cb const)
            }
        }
    };

    COMPUTE(std::integral_constant<int, 0>{});
    COMPUTE(std::integral_constant<int, 1>{});

    // row-direction: reduce across the 16 lanes (cols) sharing each row
    #pragma unroll
    for (int m = 1; m <= 8; m <<= 1)
        #pragma unroll
        for (int g = 0; g < 2; ++g)
            #pragma unroll
            for (int v = 0; v < 4; ++v)
                sumexp[g][v] += __shfl_xor(sumexp[g][v], m);

    if (l15 == 0) {
        #pragma unroll
        for (int g = 0; g < 2; ++g) {
            int row = wr0 + g * 16 + lb * 4;
            *(f32x4*)&S_contrib[(size_t)J * N_TOT + row] = sumexp[g];
        }
    }

    // col-direction: reduce lb groups per col, combine 4 waves via LDS
    if (!isdiag) {
        #pragma unroll
        for (int k = 0; k < 8; ++k) {
            float v = csr[k];
            v += __shfl_xor(v, 16);
            v += __shfl_xor(v, 32);
            if (lb == 0) colred[wv][k * 16 + l15] = v;   // col k*16+l15 of 128
        }
        __syncthreads();
        if (tid < GRP) {
            float s = colred[0][tid] + colred[1][tid] + colred[2][tid] + colred[3][tid];
            S_contrib[(size_t)I * N_TOT + cs0 + tid] = s;
        }
    }
}

// bf16-pair dot helper (uint = 2 packed bf16)
__device__ inline float bdot(unsigned a, unsigned b) {
    float alo = __uint_as_float(a << 16), ahi = __uint_as_float(a & 0xffff0000u);
    float blo = __uint_as_float(b << 16), bhi = __uint_as_float(b & 0xffff0000u);
    return fmaf(alo, blo, ahi * bhi);
}

// ---------------- kernel 3: per-row loss, block partials ----------------
// contrib_r = log(S_r) - 2*dot(zn_r, zn_partner), S_r = sum_{c!=r} exp(2*cos)
__global__ __launch_bounds__(256) void k_rowsum(const float* __restrict__ S_contrib,
                                                const __hip_bfloat16* __restrict__ zn_,
                                                float* __restrict__ blk_out) {
    const int r = blockIdx.x * 256 + threadIdx.x;
    float S = 0.0f;
    #pragma unroll
    for (int s = 0; s < NGRP; ++s) S += S_contrib[(size_t)s * N_TOT + r];

    const uint4* pa = (const uint4*)((const __bf16*)zn_ + (size_t)r * DIM);
    const uint4* pb = (const uint4*)((const __bf16*)zn_ + (size_t)(r ^ BATCH) * DIM);
    float dot = 0.0f;
    #pragma unroll
    for (int c = 0; c < DIM / 8; ++c) {
        uint4 ua = pa[c], ub = pb[c];
        dot += bdot(ua.x, ub.x) + bdot(ua.y, ub.y) + bdot(ua.z, ub.z) + bdot(ua.w, ub.w);
    }

    float contrib = __logf(S) - 2.0f * dot;

    #pragma unroll
    for (int m = 1; m < 64; m <<= 1) contrib += __shfl_xor(contrib, m);
    __shared__ float sm[4];
    if ((threadIdx.x & 63) == 0) sm[threadIdx.x >> 6] = contrib;
    __syncthreads();
    if (threadIdx.x == 0) blk_out[blockIdx.x] = sm[0] + sm[1] + sm[2] + sm[3];
}

// ---------------- kernel 4: final scalar ----------------
__global__ void k_final(const float* __restrict__ blk_out, float* __restrict__ out) {
    float v = (threadIdx.x < NROWBLK) ? blk_out[threadIdx.x] : 0.0f;
    #pragma unroll
    for (int m = 1; m < 64; m <<= 1) v += __shfl_xor(v, m);
    if (threadIdx.x == 0) out[0] = v / (float)N_TOT;
}

extern "C" void kernel_launch(void* const* d_in, const int* in_sizes, int n_in,
                              void* d_out, int out_size, void* d_ws, size_t ws_size,
                              hipStream_t stream) {
    const float* zi = (const float*)d_in[0];
    const float* zj = (const float*)d_in[1];
    char* ws = (char*)d_ws;
    __hip_bfloat16* zn = (__hip_bfloat16*)ws;                        // 2 MB
    float* S_contrib = (float*)(ws + (size_t)2 * 1024 * 1024);       // 2 MB (64 slots)
    float* blk       = (float*)(ws + (size_t)4 * 1024 * 1024);       // 128 B
    float* out       = (float*)d_out;

    k_normalize<<<N_TOT / 4, 256, 0, stream>>>(zi, zj, zn);
    k_main<<<NPAIR, 256, 0, stream>>>(zn, S_contrib);
    k_rowsum<<<NROWBLK, 256, 0, stream>>>(S_contrib, zn, blk);
    k_final<<<1, 64, 0, stream>>>(blk, out);
}